// Round 16
// baseline (104.545 us; speedup 1.0000x reference)
//
#include <hip/hip_runtime.h>
#include <hip/hip_bf16.h>

#define HID 768
#define PD 164
#define NQ 196
#define SEQ 2048

typedef __attribute__((ext_vector_type(8))) short bf16x8_t;
typedef __attribute__((ext_vector_type(4))) float f32x4_t;
typedef __attribute__((ext_vector_type(16))) float f32x16_t;
typedef __attribute__((ext_vector_type(4))) unsigned int u32x4_t;

static __device__ __forceinline__ unsigned short f2bfu(float f) {
  union { __hip_bfloat16 h; unsigned short u; } cv;
  cv.h = __float2bfloat16(f);
  return cv.u;
}

static __device__ __forceinline__ unsigned cvtpk(float a, float b) {
  unsigned r;
  asm("v_cvt_pk_bf16_f32 %0, %1, %2" : "=v"(r) : "v"(a), "v"(b));
  return r;
}

static __device__ __forceinline__ void gload16(const void* g, void* l) {
  __builtin_amdgcn_global_load_lds(
      (const __attribute__((address_space(1))) void*)g,
      (__attribute__((address_space(3))) void*)l, 16, 0, 0);
}

// ---------------- prep: qkv_w -> bf16 (padded) only ----------------
__global__ __launch_bounds__(256) void k_prep_q(const float* __restrict__ qkv_w,
                                                unsigned short* __restrict__ qwb) {
  int i = (blockIdx.x * 256 + threadIdx.x) * 4;     // 208*192 = 39936 elems
  if (i >= 39936) return;
  int n = i / 192, k = i - n * 192;
  float v0 = (n < NQ && k + 0 < PD) ? qkv_w[n * PD + k + 0] : 0.f;
  float v1 = (n < NQ && k + 1 < PD) ? qkv_w[n * PD + k + 1] : 0.f;
  float v2 = (n < NQ && k + 2 < PD) ? qkv_w[n * PD + k + 2] : 0.f;
  float v3 = (n < NQ && k + 3 < PD) ? qkv_w[n * PD + k + 3] : 0.f;
  ushort4 o;
  o.x = f2bfu(v0); o.y = f2bfu(v1); o.z = f2bfu(v2); o.w = f2bfu(v3);
  *(ushort4*)(qwb + i) = o;
}

// ---------------- fused LN + x2 convert + QKV GEMM (+ wb convert blocks) ----------------
// v2: xr LDS staging REMOVED (two-pass global read of x1; L2-hot on 2nd pass).
// LDS 70 -> 26 KB => ~5 blocks/CU (was 2). Phase 1: per-lane stride-4 float4 quads,
// regs + shuffle reduce. Phase 2: coalesced float2 re-read, normalize -> Aq bf16.
// blocks 256..831: convert out_w -> wb bf16 (consumer is k_out, two launches later).
__global__ __launch_bounds__(256, 4) void k_lnqkv(const float* __restrict__ hidden,
                                                  const float* __restrict__ lns,
                                                  const float* __restrict__ lnb,
                                                  const unsigned short* __restrict__ qwb,
                                                  const float* __restrict__ qkv_b,
                                                  const float* __restrict__ out_w,
                                                  unsigned short* __restrict__ wbo,
                                                  unsigned short* __restrict__ merged,
                                                  unsigned short* __restrict__ qg,
                                                  unsigned short* __restrict__ kg,
                                                  unsigned short* __restrict__ v16) {
  __shared__ unsigned short Aq[64][200];   // x1n bf16; cols 164..191 zero
  __shared__ float stats[64][2];
  int t = threadIdx.x;
  if (blockIdx.x >= 256) {                 // ---- wb converter blocks ----
    int i = ((blockIdx.x - 256) * 256 + t) * 4;     // 768*768 = 589824 elems
    float4 v = *(const float4*)(out_w + i);
    ushort4 o;
    o.x = f2bfu(v.x); o.y = f2bfu(v.y); o.z = f2bfu(v.z); o.w = f2bfu(v.w);
    *(ushort4*)(wbo + i) = o;
    return;
  }
  int r0 = blockIdx.x * 64;
  int l = t & 63, w = t >> 6;
  // ---- phase 1: stats straight from global (regs + shuffle reduce) ----
  {
    int row = w * 16 + (l & 15), g = l >> 4;
    const float* xrow = hidden + (size_t)(r0 + row) * HID;
    float sum = 0.f, sq = 0.f;
    for (int j = g; j < 41; j += 4) {      // float4-quads, stride 4 -> 16B aligned
      float4 v = *(const float4*)(xrow + j * 4);
      sum += v.x + v.y + v.z + v.w;
      sq  += v.x * v.x + v.y * v.y + v.z * v.z + v.w * v.w;
    }
    sum += __shfl_xor(sum, 16, 64); sum += __shfl_xor(sum, 32, 64);
    sq  += __shfl_xor(sq, 16, 64);  sq  += __shfl_xor(sq, 32, 64);
    float mean = sum * (1.f / PD);
    float var = sq * (1.f / PD) - mean * mean;
    float rstd = rsqrtf(var + 1e-5f);
    if (g == 0) { stats[row][0] = mean; stats[row][1] = rstd; }
  }
  __syncthreads();
  // ---- phase 2: normalize (coalesced L2-hot re-read) -> Aq bf16 ----
  #pragma unroll
  for (int i = 0; i < 24; i++) {
    int idx = t + i * 256;                 // 64 rows * 96 pairs (192 cols)
    int row = idx / 96, c2 = idx - row * 96;
    int d = c2 * 2;
    float mean = stats[row][0], rstd = stats[row][1];
    float2 v = *(const float2*)(hidden + (size_t)(r0 + row) * HID + d);  // d<=190<768
    float v0 = (d < PD)     ? (v.x - mean) * rstd * lns[d]     + lnb[d]     : 0.f;
    float v1 = (d + 1 < PD) ? (v.y - mean) * rstd * lns[d + 1] + lnb[d + 1] : 0.f;
    unsigned int pk = (unsigned int)f2bfu(v0) | ((unsigned int)f2bfu(v1) << 16);
    *(unsigned int*)(&Aq[row][d]) = pk;
  }
  // ---- phase 3: x2 convert -> merged ----
  #pragma unroll
  for (int i = 0; i < 38; i++) {
    int idx = t + i * 256;                 // 64 rows * 151 quads = 9664
    if (idx < 9664) {
      int row = idx / 151, q = idx - row * 151;
      int d = PD + q * 4;
      float4 v = *(const float4*)(hidden + (size_t)(r0 + row) * HID + d);
      ushort4 o;
      o.x = f2bfu(v.x); o.y = f2bfu(v.y); o.z = f2bfu(v.z); o.w = f2bfu(v.w);
      *(ushort4*)(merged + (size_t)(r0 + row) * HID + d) = o;
    }
  }
  __syncthreads();
  // ---- phase 4: QKV GEMM: A from LDS, B from L2 ----
  int lr15 = l & 15, g = l >> 4;
  f32x4_t acc[13];
  #pragma unroll
  for (int n = 0; n < 13; n++) acc[n] = (f32x4_t){0.f, 0.f, 0.f, 0.f};
  #pragma unroll 2
  for (int kc = 0; kc < 6; kc++) {
    bf16x8_t a = *(const bf16x8_t*)(&Aq[w * 16 + lr15][kc * 32 + g * 8]);
    #pragma unroll
    for (int n = 0; n < 13; n++) {
      bf16x8_t b = *(const bf16x8_t*)(qwb + (size_t)(n * 16 + lr15) * 192 + kc * 32 + g * 8);
      acc[n] = __builtin_amdgcn_mfma_f32_16x16x32_bf16(a, b, acc[n], 0, 0, 0);
    }
  }
  // ---- epilogue ----
  {
    float bias = qkv_b[lr15];
    #pragma unroll
    for (int r = 0; r < 4; r++) {
      int grow = r0 + w * 16 + g * 4 + r;
      qg[(size_t)grow * 16 + lr15] = f2bfu((acc[0][r] + bias) * 0.36067376022224085f); // 0.25*log2(e)
    }
  }
  {
    float bias = qkv_b[16 + lr15];
    #pragma unroll
    for (int r = 0; r < 4; r++) {
      int grow = r0 + w * 16 + g * 4 + r;
      kg[(size_t)grow * 16 + lr15] = f2bfu(acc[1][r] + bias);
    }
  }
  int s0 = (r0 & 2047) + w * 16;
  int bb = r0 >> 11;
  size_t vrowbase = (size_t)(bb * 128 + (s0 >> 4)) * 192;
  #pragma unroll
  for (int n = 2; n < 13; n++) {
    int col = n * 16 + lr15;
    int d = col - 32;                      // 0..175
    float bias = (col < NQ) ? qkv_b[col] : 0.f;
    float v0 = acc[n][0] + bias, v1 = acc[n][1] + bias;
    float v2 = acc[n][2] + bias, v3 = acc[n][3] + bias;
    if (d == 164) { v0 = v1 = v2 = v3 = 1.f; }        // ones row: free denominator
    else if (d >= PD) { v0 = v1 = v2 = v3 = 0.f; }
    ushort4 o;
    o.x = f2bfu(v0); o.y = f2bfu(v1); o.z = f2bfu(v2); o.w = f2bfu(v3);
    *(ushort4*)(v16 + (vrowbase + d) * 16 + g * 4) = o;
  }
}

// ---------------- flash attention v5 (proven, FROZEN) ----------------
__global__ __launch_bounds__(256, 2) void k_attn(const unsigned short* __restrict__ qg,
                                                 const unsigned short* __restrict__ kg,
                                                 const unsigned short* __restrict__ v16,
                                                 unsigned short* __restrict__ merged) {
  __shared__ float red[2][64 * 98];
  int t = threadIdx.x;
  int w = t >> 6, l = t & 63;
  int b = blockIdx.x & 7, qt = blockIdx.x >> 3;
  int lo = l & 31, hi = l >> 5;
  int qbase = b * SEQ + qt * 32;
  bf16x8_t qf = *(const bf16x8_t*)(qg + (size_t)(qbase + lo) * 16 + hi * 8);
  const unsigned short* kb = kg + (size_t)b * SEQ * 16;
  const unsigned short* vbb = v16 + (size_t)b * 128 * 192 * 16;
  f32x16_t zro;
  #pragma unroll
  for (int r = 0; r < 16; r++) zro[r] = 0.f;
  f32x16_t acc[6];
  #pragma unroll
  for (int f = 0; f < 6; f++) acc[f] = zro;

  int it0 = w * 8;
  bf16x8_t kf0 = *(const bf16x8_t*)(kb + (size_t)(it0 * 64 + lo) * 16 + hi * 8);
  bf16x8_t kf1 = *(const bf16x8_t*)(kb + (size_t)(it0 * 64 + 32 + lo) * 16 + hi * 8);
  bf16x8_t va[6], vb_[6];
  {
    const unsigned short* vt0 = vbb + (size_t)(it0 * 4) * (192 * 16) + hi * 8;
    #pragma unroll
    for (int f = 0; f < 6; f++) va[f] = *(const bf16x8_t*)(vt0 + (f * 32 + lo) * 16);
  }
  for (int it = it0; it < it0 + 8; ++it) {
    bf16x8_t nk0 = *(const bf16x8_t*)(kb + (size_t)((it + 1) * 64 + lo) * 16 + hi * 8);
    bf16x8_t nk1 = *(const bf16x8_t*)(kb + (size_t)((it + 1) * 64 + 32 + lo) * 16 + hi * 8);
    f32x16_t sc0 = __builtin_amdgcn_mfma_f32_32x32x16_bf16(kf0, qf, zro, 0, 0, 0);
    f32x16_t sc1 = __builtin_amdgcn_mfma_f32_32x32x16_bf16(kf1, qf, zro, 0, 0, 0);
    bf16x8_t pa[4];
    #pragma unroll
    for (int jt = 0; jt < 2; ++jt) {
      f32x16_t sc = jt ? sc1 : sc0;
      unsigned u[8];
      #pragma unroll
      for (int k = 0; k < 8; ++k)
        u[k] = cvtpk(exp2f(sc[2 * k]), exp2f(sc[2 * k + 1]));
      asm volatile("v_permlane32_swap_b32 %0, %1" : "+v"(u[0]), "+v"(u[2]));
      asm volatile("v_permlane32_swap_b32 %0, %1" : "+v"(u[1]), "+v"(u[3]));
      asm volatile("v_permlane32_swap_b32 %0, %1" : "+v"(u[4]), "+v"(u[6]));
      asm volatile("v_permlane32_swap_b32 %0, %1" : "+v"(u[5]), "+v"(u[7]));
      union { u32x4_t u4; bf16x8_t h8; } c0, c1;
      c0.u4 = (u32x4_t){u[0], u[1], u[2], u[3]};
      c1.u4 = (u32x4_t){u[4], u[5], u[6], u[7]};
      pa[jt * 2 + 0] = c0.h8;
      pa[jt * 2 + 1] = c1.h8;
    }
#define PV_STEP(JS, VCUR, VNXT, NT, NJS)                                            \
    {                                                                               \
      const unsigned short* vtn = vbb + (size_t)((NT) * 4 + (NJS)) * (192 * 16) + hi * 8; \
      _Pragma("unroll")                                                             \
      for (int f = 0; f < 6; f++) VNXT[f] = *(const bf16x8_t*)(vtn + (f * 32 + lo) * 16); \
      _Pragma("unroll")                                                             \
      for (int f = 0; f < 6; f++)                                                   \
        acc[f] = __builtin_amdgcn_mfma_f32_32x32x16_bf16(pa[JS], VCUR[f], acc[f], 0, 0, 0); \
    }
    PV_STEP(0, va,  vb_, it, 1)
    PV_STEP(1, vb_, va,  it, 2)
    PV_STEP(2, va,  vb_, it, 3)
    PV_STEP(3, vb_, va,  it + 1, 0)
#undef PV_STEP
    kf0 = nk0; kf1 = nk1;
  }

  if (w >= 2) {
    float* dst = &red[w - 2][l * 98];
    #pragma unroll
    for (int f = 0; f < 6; f++)
      #pragma unroll
      for (int r = 0; r < 16; r += 2)
        *(float2*)(dst + f * 16 + r) = make_float2(acc[f][r], acc[f][r + 1]);
  }
  __syncthreads();
  if (w < 2) {
    const float* src = &red[w][l * 98];
    #pragma unroll
    for (int f = 0; f < 6; f++)
      #pragma unroll
      for (int r = 0; r < 16; r += 2) {
        float2 v = *(const float2*)(src + f * 16 + r);
        acc[f][r] += v.x; acc[f][r + 1] += v.y;
      }
  }
  __syncthreads();
  if (w == 1) {
    float* dst = &red[0][l * 98];
    #pragma unroll
    for (int f = 0; f < 6; f++)
      #pragma unroll
      for (int r = 0; r < 16; r += 2)
        *(float2*)(dst + f * 16 + r) = make_float2(acc[f][r], acc[f][r + 1]);
  }
  __syncthreads();
  if (w == 0) {
    const float* src = &red[0][l * 98];
    #pragma unroll
    for (int f = 0; f < 6; f++)
      #pragma unroll
      for (int r = 0; r < 16; r += 2) {
        float2 v = *(const float2*)(src + f * 16 + r);
        acc[f][r] += v.x; acc[f][r + 1] += v.y;
      }
    float dninv[16];
    #pragma unroll
    for (int r = 0; r < 16; ++r)
      dninv[r] = 1.0f / __shfl(acc[5][r], 4 + hi * 32, 64);
    #pragma unroll
    for (int f = 0; f < 6; ++f) {
      int d = f * 32 + lo;
      if (d < PD) {
        #pragma unroll
        for (int r = 0; r < 16; ++r) {
          int q = qbase + (r & 3) + 8 * (r >> 2) + 4 * hi;
          merged[(size_t)q * HID + d] = f2bfu(acc[f][r] * dninv[r]);
        }
      }
    }
  }
}

// ---------------- out GEMM v5 (R11 exact, proven ~33us — FROZEN) --------------------
__global__ __launch_bounds__(256, 3) void k_out(const unsigned short* __restrict__ mg,
                                                const unsigned short* __restrict__ wb,
                                                const float* __restrict__ out_b,
                                                float* __restrict__ out) {
  __shared__ unsigned short Al[2][128 * 32];   // 16 KB
  __shared__ unsigned short Bl[2][128 * 32];   // 16 KB
  int t = threadIdx.x;
  int bid = blockIdx.x;
  int wgid = (bid & 7) * 96 + (bid >> 3);      // bijective: 768 = 8*96
  int nb = wgid % 6, mb = wgid / 6;
  int m0 = mb * 128, n0 = nb * 128;
  int l = t & 63, w = t >> 6, wr = w >> 1, wc = w & 1;
  int lr = l & 15, lg = l >> 4;
  int sw = (lr >> 1) & 3;
  f32x4_t acc[4][4];
  #pragma unroll
  for (int mi = 0; mi < 4; mi++)
    #pragma unroll
    for (int ni = 0; ni < 4; ni++) acc[mi][ni] = (f32x4_t){0.f, 0.f, 0.f, 0.f};

  auto stage = [&](int buf, int kt) {          // 2 A + 2 B gload16 per thread
    #pragma unroll
    for (int i = 0; i < 2; i++) {
      int off = t + i * 256;                   // 512 x 16B = 128x32 bf16
      int row = off >> 2, c = off & 3;
      int cs = c ^ ((row >> 1) & 3);           // inverse swizzle on SOURCE
      gload16(mg + (size_t)(m0 + row) * HID + kt * 32 + cs * 8, (char*)&Al[buf][0] + off * 16);
    }
    #pragma unroll
    for (int i = 0; i < 2; i++) {
      int off = t + i * 256;
      int row = off >> 2, c = off & 3;
      int cs = c ^ ((row >> 1) & 3);
      gload16(wb + (size_t)(n0 + row) * HID + kt * 32 + cs * 8, (char*)&Bl[buf][0] + off * 16);
    }
  };
  auto compute = [&](int cur) {                // 16 MFMAs (K=32 per step)
    __builtin_amdgcn_s_setprio(1);
    bf16x8_t a[4], bfr[4];
    int slot = lg ^ sw;
    #pragma unroll
    for (int mi = 0; mi < 4; mi++)
      a[mi] = *(const bf16x8_t*)(&Al[cur][(wr * 64 + mi * 16 + lr) * 32 + slot * 8]);
    #pragma unroll
    for (int ni = 0; ni < 4; ni++)
      bfr[ni] = *(const bf16x8_t*)(&Bl[cur][(wc * 64 + ni * 16 + lr) * 32 + slot * 8]);
    #pragma unroll
    for (int mi = 0; mi < 4; mi++)
      #pragma unroll
      for (int ni = 0; ni < 4; ni++)
        acc[mi][ni] = __builtin_amdgcn_mfma_f32_16x16x32_bf16(a[mi], bfr[ni], acc[mi][ni], 0, 0, 0);
    __builtin_amdgcn_s_setprio(0);
  };

  stage(0, 0);
  stage(1, 1);                                 // 8 loads in flight
  for (int kt = 0; kt < 23; kt++) {
    int cur = kt & 1;
    asm volatile("s_waitcnt vmcnt(4)" ::: "memory");     // stage(kt) landed; stage(kt+1) in flight
    __builtin_amdgcn_sched_barrier(0);
    __builtin_amdgcn_s_barrier();
    compute(cur);
    asm volatile("s_waitcnt lgkmcnt(0)" ::: "memory");   // my ds_reads of buf[cur] done
    __builtin_amdgcn_sched_barrier(0);
    __builtin_amdgcn_s_barrier();
    if (kt + 2 < 24) stage(cur, kt + 2);
  }
  asm volatile("s_waitcnt vmcnt(0)" ::: "memory");
  __builtin_amdgcn_sched_barrier(0);
  __builtin_amdgcn_s_barrier();
  compute(1);                                  // kt = 23

  #pragma unroll
  for (int ni = 0; ni < 4; ni++) {
    int col = n0 + wc * 64 + ni * 16 + lr;
    float bias = out_b[col];
    #pragma unroll
    for (int mi = 0; mi < 4; mi++) {
      #pragma unroll
      for (int r = 0; r < 4; r++) {
        int row = m0 + wr * 64 + mi * 16 + lg * 4 + r;
        out[(size_t)row * HID + col] = acc[mi][ni][r] + bias;
      }
    }
  }
}

extern "C" void kernel_launch(void* const* d_in, const int* in_sizes, int n_in,
                              void* d_out, int out_size, void* d_ws, size_t ws_size,
                              hipStream_t stream) {
  const float* hidden = (const float*)d_in[0];
  const float* lns    = (const float*)d_in[1];
  const float* lnb    = (const float*)d_in[2];
  const float* qkv_w  = (const float*)d_in[3];
  const float* qkv_b  = (const float*)d_in[4];
  const float* out_w  = (const float*)d_in[5];
  const float* out_b  = (const float*)d_in[6];
  char* ws = (char*)d_ws;
  unsigned short* qg  = (unsigned short*)(ws + 0);          // 16384*16*2      =   524288
  unsigned short* kg  = (unsigned short*)(ws + 524288);     // 16384*16*2      =   524288
  unsigned short* v16 = (unsigned short*)(ws + 1048576);    // 8*128*192*16*2  =  6291456
  unsigned short* qwb = (unsigned short*)(ws + 13631488);   // 208*192*2       =    79872
  unsigned short* wb  = (unsigned short*)(ws + 13711360);   // 768*768*2       =  1179648
  unsigned short* mg  = (unsigned short*)(ws + 14891008);   // 16384*768*2     = 25165824 (end 40056832)
  hipLaunchKernelGGL(k_prep_q, dim3(39),  dim3(256), 0, stream, qkv_w, qwb);
  hipLaunchKernelGGL(k_lnqkv,  dim3(832), dim3(256), 0, stream, hidden, lns, lnb, qwb, qkv_b,
                     out_w, wb, mg, qg, kg, v16);
  hipLaunchKernelGGL(k_attn,   dim3(512), dim3(256), 0, stream, qg, kg, v16, mg);
  hipLaunchKernelGGL(k_out,    dim3(768), dim3(256), 0, stream, mg, wb, out_b, (float*)d_out);
}

// Round 17
// 93.799 us; speedup vs baseline: 1.1146x; 1.1146x over previous
//
#include <hip/hip_runtime.h>
#include <hip/hip_bf16.h>

#define HID 768
#define PD 164
#define NQ 196
#define SEQ 2048

typedef __attribute__((ext_vector_type(8))) short bf16x8_t;
typedef __attribute__((ext_vector_type(4))) float f32x4_t;
typedef __attribute__((ext_vector_type(16))) float f32x16_t;
typedef __attribute__((ext_vector_type(4))) unsigned int u32x4_t;

static __device__ __forceinline__ unsigned short f2bfu(float f) {
  union { __hip_bfloat16 h; unsigned short u; } cv;
  cv.h = __float2bfloat16(f);
  return cv.u;
}

static __device__ __forceinline__ unsigned cvtpk(float a, float b) {
  unsigned r;
  asm("v_cvt_pk_bf16_f32 %0, %1, %2" : "=v"(r) : "v"(a), "v"(b));
  return r;
}

static __device__ __forceinline__ void gload16(const void* g, void* l) {
  __builtin_amdgcn_global_load_lds(
      (const __attribute__((address_space(1))) void*)g,
      (__attribute__((address_space(3))) void*)l, 16, 0, 0);
}

// ---------------- prep: qkv_w -> bf16 (padded) only ----------------
__global__ __launch_bounds__(256) void k_prep_q(const float* __restrict__ qkv_w,
                                                unsigned short* __restrict__ qwb) {
  int i = (blockIdx.x * 256 + threadIdx.x) * 4;     // 208*192 = 39936 elems
  if (i >= 39936) return;
  int n = i / 192, k = i - n * 192;
  float v0 = (n < NQ && k + 0 < PD) ? qkv_w[n * PD + k + 0] : 0.f;
  float v1 = (n < NQ && k + 1 < PD) ? qkv_w[n * PD + k + 1] : 0.f;
  float v2 = (n < NQ && k + 2 < PD) ? qkv_w[n * PD + k + 2] : 0.f;
  float v3 = (n < NQ && k + 3 < PD) ? qkv_w[n * PD + k + 3] : 0.f;
  ushort4 o;
  o.x = f2bfu(v0); o.y = f2bfu(v1); o.z = f2bfu(v2); o.w = f2bfu(v3);
  *(ushort4*)(qwb + i) = o;
}

// ---------------- fused LN + x2 convert + QKV GEMM (+ wb convert blocks) ----------------
// v3: R15 xr-LDS structure, 32 rows/block x 512 LN blocks (grid was the occupancy cap:
// 256 blocks = 1/CU). LDS 34.3 KB -> 2 blocks/CU by grid, 4 by LDS => 8 waves/CU (2x).
// GEMM per wave: wr = w&1 (16-row tile), nh = w>>1 (n-half: 0..6 / 7..12).
// blocks 512..1087: convert out_w -> wb (consumer k_out, two launches later).
__global__ __launch_bounds__(256, 4) void k_lnqkv(const float* __restrict__ hidden,
                                                  const float* __restrict__ lns,
                                                  const float* __restrict__ lnb,
                                                  const unsigned short* __restrict__ qwb,
                                                  const float* __restrict__ qkv_b,
                                                  const float* __restrict__ out_w,
                                                  unsigned short* __restrict__ wbo,
                                                  unsigned short* __restrict__ merged,
                                                  unsigned short* __restrict__ qg,
                                                  unsigned short* __restrict__ kg,
                                                  unsigned short* __restrict__ v16) {
  __shared__ float xr[32][172];
  __shared__ float stats[32][2];
  __shared__ unsigned short Aq[32][200];   // x1n bf16; cols 164..191 zero
  int t = threadIdx.x;
  if (blockIdx.x >= 512) {                 // ---- wb converter blocks ----
    int i = ((blockIdx.x - 512) * 256 + t) * 4;     // 768*768 = 589824 elems
    float4 v = *(const float4*)(out_w + i);
    ushort4 o;
    o.x = f2bfu(v.x); o.y = f2bfu(v.y); o.z = f2bfu(v.z); o.w = f2bfu(v.w);
    *(ushort4*)(wbo + i) = o;
    return;
  }
  int r0 = blockIdx.x * 32;
  int l = t & 63, w = t >> 6;
  // ---- load x1 rows into LDS (32 rows x 41 quads = 1312 float4) ----
  #pragma unroll
  for (int i = 0; i < 6; i++) {
    int idx = t + i * 256;
    if (idx < 1312) {
      int row = idx / 41, q = idx - row * 41;
      float4 v = *(const float4*)(hidden + (size_t)(r0 + row) * HID + q * 4);
      *(float4*)&xr[row][q * 4] = v;
    }
  }
  __syncthreads();
  // ---- stats: 8 lanes per row (row = w*8 + (l&7), g8 = l>>3) ----
  {
    int row = w * 8 + (l & 7), g8 = l >> 3;
    float sum = 0.f, sq = 0.f;
    for (int j = g8; j < 41; j += 8) {
      float4 v = *(const float4*)&xr[row][j * 4];
      sum += v.x + v.y + v.z + v.w;
      sq  += v.x * v.x + v.y * v.y + v.z * v.z + v.w * v.w;
    }
    sum += __shfl_xor(sum, 8, 64); sum += __shfl_xor(sum, 16, 64); sum += __shfl_xor(sum, 32, 64);
    sq  += __shfl_xor(sq, 8, 64);  sq  += __shfl_xor(sq, 16, 64);  sq  += __shfl_xor(sq, 32, 64);
    float mean = sum * (1.f / PD);
    float var = sq * (1.f / PD) - mean * mean;
    float rstd = rsqrtf(var + 1e-5f);
    if (g8 == 0) { stats[row][0] = mean; stats[row][1] = rstd; }
  }
  __syncthreads();
  // ---- normalize -> Aq bf16 (32 rows x 96 pairs = 3072) ----
  #pragma unroll
  for (int i = 0; i < 12; i++) {
    int idx = t + i * 256;
    int row = idx / 96, c2 = idx - row * 96;
    int d = c2 * 2;
    float mean = stats[row][0], rstd = stats[row][1];
    float v0 = (d < PD)     ? (xr[row][d]     - mean) * rstd * lns[d]     + lnb[d]     : 0.f;
    float v1 = (d + 1 < PD) ? (xr[row][d + 1] - mean) * rstd * lns[d + 1] + lnb[d + 1] : 0.f;
    unsigned int pk = (unsigned int)f2bfu(v0) | ((unsigned int)f2bfu(v1) << 16);
    *(unsigned int*)(&Aq[row][d]) = pk;
  }
  // ---- x2 convert -> merged (32 rows x 151 quads = 4832) ----
  #pragma unroll
  for (int i = 0; i < 19; i++) {
    int idx = t + i * 256;
    if (idx < 4832) {
      int row = idx / 151, q = idx - row * 151;
      int d = PD + q * 4;
      float4 v = *(const float4*)(hidden + (size_t)(r0 + row) * HID + d);
      ushort4 o;
      o.x = f2bfu(v.x); o.y = f2bfu(v.y); o.z = f2bfu(v.z); o.w = f2bfu(v.w);
      *(ushort4*)(merged + (size_t)(r0 + row) * HID + d) = o;
    }
  }
  __syncthreads();
  // ---- QKV GEMM: A from LDS, B from L2. wr = row-tile, nh = n-half ----
  int lr15 = l & 15, g = l >> 4;
  int wr = w & 1, nh = w >> 1;
  int nbase = nh ? 7 : 0;
  int ncnt  = nh ? 6 : 7;
  f32x4_t acc[7];
  #pragma unroll
  for (int n = 0; n < 7; n++) acc[n] = (f32x4_t){0.f, 0.f, 0.f, 0.f};
  #pragma unroll 2
  for (int kc = 0; kc < 6; kc++) {
    bf16x8_t a = *(const bf16x8_t*)(&Aq[wr * 16 + lr15][kc * 32 + g * 8]);
    #pragma unroll
    for (int ni = 0; ni < 7; ni++) {
      if (ni < ncnt) {
        int n = nbase + ni;
        bf16x8_t b = *(const bf16x8_t*)(qwb + (size_t)(n * 16 + lr15) * 192 + kc * 32 + g * 8);
        acc[ni] = __builtin_amdgcn_mfma_f32_16x16x32_bf16(a, b, acc[ni], 0, 0, 0);
      }
    }
  }
  // ---- epilogue ----
  int s0 = (r0 & 2047) + wr * 16;
  int bb = r0 >> 11;
  size_t vrowbase = (size_t)(bb * 128 + (s0 >> 4)) * 192;
  if (nh == 0) {
    {
      float bias = qkv_b[lr15];
      #pragma unroll
      for (int r = 0; r < 4; r++) {
        int grow = r0 + wr * 16 + g * 4 + r;
        qg[(size_t)grow * 16 + lr15] = f2bfu((acc[0][r] + bias) * 0.36067376022224085f); // 0.25*log2(e)
      }
    }
    {
      float bias = qkv_b[16 + lr15];
      #pragma unroll
      for (int r = 0; r < 4; r++) {
        int grow = r0 + wr * 16 + g * 4 + r;
        kg[(size_t)grow * 16 + lr15] = f2bfu(acc[1][r] + bias);
      }
    }
    #pragma unroll
    for (int ni = 2; ni < 7; ni++) {
      int col = ni * 16 + lr15;
      int d = col - 32;                    // 0..79
      float bias = qkv_b[col];
      ushort4 o;
      o.x = f2bfu(acc[ni][0] + bias); o.y = f2bfu(acc[ni][1] + bias);
      o.z = f2bfu(acc[ni][2] + bias); o.w = f2bfu(acc[ni][3] + bias);
      *(ushort4*)(v16 + (vrowbase + d) * 16 + g * 4) = o;
    }
  } else {
    #pragma unroll
    for (int ni = 0; ni < 6; ni++) {
      int col = (7 + ni) * 16 + lr15;
      int d = col - 32;                    // 80..175
      float bias = (col < NQ) ? qkv_b[col] : 0.f;
      float v0 = acc[ni][0] + bias, v1 = acc[ni][1] + bias;
      float v2 = acc[ni][2] + bias, v3 = acc[ni][3] + bias;
      if (d == 164) { v0 = v1 = v2 = v3 = 1.f; }      // ones row: free denominator
      else if (d >= PD) { v0 = v1 = v2 = v3 = 0.f; }
      ushort4 o;
      o.x = f2bfu(v0); o.y = f2bfu(v1); o.z = f2bfu(v2); o.w = f2bfu(v3);
      *(ushort4*)(v16 + (vrowbase + d) * 16 + g * 4) = o;
    }
  }
}

// ---------------- flash attention v5 (proven, FROZEN) ----------------
__global__ __launch_bounds__(256, 2) void k_attn(const unsigned short* __restrict__ qg,
                                                 const unsigned short* __restrict__ kg,
                                                 const unsigned short* __restrict__ v16,
                                                 unsigned short* __restrict__ merged) {
  __shared__ float red[2][64 * 98];
  int t = threadIdx.x;
  int w = t >> 6, l = t & 63;
  int b = blockIdx.x & 7, qt = blockIdx.x >> 3;
  int lo = l & 31, hi = l >> 5;
  int qbase = b * SEQ + qt * 32;
  bf16x8_t qf = *(const bf16x8_t*)(qg + (size_t)(qbase + lo) * 16 + hi * 8);
  const unsigned short* kb = kg + (size_t)b * SEQ * 16;
  const unsigned short* vbb = v16 + (size_t)b * 128 * 192 * 16;
  f32x16_t zro;
  #pragma unroll
  for (int r = 0; r < 16; r++) zro[r] = 0.f;
  f32x16_t acc[6];
  #pragma unroll
  for (int f = 0; f < 6; f++) acc[f] = zro;

  int it0 = w * 8;
  bf16x8_t kf0 = *(const bf16x8_t*)(kb + (size_t)(it0 * 64 + lo) * 16 + hi * 8);
  bf16x8_t kf1 = *(const bf16x8_t*)(kb + (size_t)(it0 * 64 + 32 + lo) * 16 + hi * 8);
  bf16x8_t va[6], vb_[6];
  {
    const unsigned short* vt0 = vbb + (size_t)(it0 * 4) * (192 * 16) + hi * 8;
    #pragma unroll
    for (int f = 0; f < 6; f++) va[f] = *(const bf16x8_t*)(vt0 + (f * 32 + lo) * 16);
  }
  for (int it = it0; it < it0 + 8; ++it) {
    bf16x8_t nk0 = *(const bf16x8_t*)(kb + (size_t)((it + 1) * 64 + lo) * 16 + hi * 8);
    bf16x8_t nk1 = *(const bf16x8_t*)(kb + (size_t)((it + 1) * 64 + 32 + lo) * 16 + hi * 8);
    f32x16_t sc0 = __builtin_amdgcn_mfma_f32_32x32x16_bf16(kf0, qf, zro, 0, 0, 0);
    f32x16_t sc1 = __builtin_amdgcn_mfma_f32_32x32x16_bf16(kf1, qf, zro, 0, 0, 0);
    bf16x8_t pa[4];
    #pragma unroll
    for (int jt = 0; jt < 2; ++jt) {
      f32x16_t sc = jt ? sc1 : sc0;
      unsigned u[8];
      #pragma unroll
      for (int k = 0; k < 8; ++k)
        u[k] = cvtpk(exp2f(sc[2 * k]), exp2f(sc[2 * k + 1]));
      asm volatile("v_permlane32_swap_b32 %0, %1" : "+v"(u[0]), "+v"(u[2]));
      asm volatile("v_permlane32_swap_b32 %0, %1" : "+v"(u[1]), "+v"(u[3]));
      asm volatile("v_permlane32_swap_b32 %0, %1" : "+v"(u[4]), "+v"(u[6]));
      asm volatile("v_permlane32_swap_b32 %0, %1" : "+v"(u[5]), "+v"(u[7]));
      union { u32x4_t u4; bf16x8_t h8; } c0, c1;
      c0.u4 = (u32x4_t){u[0], u[1], u[2], u[3]};
      c1.u4 = (u32x4_t){u[4], u[5], u[6], u[7]};
      pa[jt * 2 + 0] = c0.h8;
      pa[jt * 2 + 1] = c1.h8;
    }
#define PV_STEP(JS, VCUR, VNXT, NT, NJS)                                            \
    {                                                                               \
      const unsigned short* vtn = vbb + (size_t)((NT) * 4 + (NJS)) * (192 * 16) + hi * 8; \
      _Pragma("unroll")                                                             \
      for (int f = 0; f < 6; f++) VNXT[f] = *(const bf16x8_t*)(vtn + (f * 32 + lo) * 16); \
      _Pragma("unroll")                                                             \
      for (int f = 0; f < 6; f++)                                                   \
        acc[f] = __builtin_amdgcn_mfma_f32_32x32x16_bf16(pa[JS], VCUR[f], acc[f], 0, 0, 0); \
    }
    PV_STEP(0, va,  vb_, it, 1)
    PV_STEP(1, vb_, va,  it, 2)
    PV_STEP(2, va,  vb_, it, 3)
    PV_STEP(3, vb_, va,  it + 1, 0)
#undef PV_STEP
    kf0 = nk0; kf1 = nk1;
  }

  if (w >= 2) {
    float* dst = &red[w - 2][l * 98];
    #pragma unroll
    for (int f = 0; f < 6; f++)
      #pragma unroll
      for (int r = 0; r < 16; r += 2)
        *(float2*)(dst + f * 16 + r) = make_float2(acc[f][r], acc[f][r + 1]);
  }
  __syncthreads();
  if (w < 2) {
    const float* src = &red[w][l * 98];
    #pragma unroll
    for (int f = 0; f < 6; f++)
      #pragma unroll
      for (int r = 0; r < 16; r += 2) {
        float2 v = *(const float2*)(src + f * 16 + r);
        acc[f][r] += v.x; acc[f][r + 1] += v.y;
      }
  }
  __syncthreads();
  if (w == 1) {
    float* dst = &red[0][l * 98];
    #pragma unroll
    for (int f = 0; f < 6; f++)
      #pragma unroll
      for (int r = 0; r < 16; r += 2)
        *(float2*)(dst + f * 16 + r) = make_float2(acc[f][r], acc[f][r + 1]);
  }
  __syncthreads();
  if (w == 0) {
    const float* src = &red[0][l * 98];
    #pragma unroll
    for (int f = 0; f < 6; f++)
      #pragma unroll
      for (int r = 0; r < 16; r += 2) {
        float2 v = *(const float2*)(src + f * 16 + r);
        acc[f][r] += v.x; acc[f][r + 1] += v.y;
      }
    float dninv[16];
    #pragma unroll
    for (int r = 0; r < 16; ++r)
      dninv[r] = 1.0f / __shfl(acc[5][r], 4 + hi * 32, 64);
    #pragma unroll
    for (int f = 0; f < 6; ++f) {
      int d = f * 32 + lo;
      if (d < PD) {
        #pragma unroll
        for (int r = 0; r < 16; ++r) {
          int q = qbase + (r & 3) + 8 * (r >> 2) + 4 * hi;
          merged[(size_t)q * HID + d] = f2bfu(acc[f][r] * dninv[r]);
        }
      }
    }
  }
}

// ---------------- out GEMM v5 (R11 exact, proven ~33us — FROZEN) --------------------
__global__ __launch_bounds__(256, 3) void k_out(const unsigned short* __restrict__ mg,
                                                const unsigned short* __restrict__ wb,
                                                const float* __restrict__ out_b,
                                                float* __restrict__ out) {
  __shared__ unsigned short Al[2][128 * 32];   // 16 KB
  __shared__ unsigned short Bl[2][128 * 32];   // 16 KB
  int t = threadIdx.x;
  int bid = blockIdx.x;
  int wgid = (bid & 7) * 96 + (bid >> 3);      // bijective: 768 = 8*96
  int nb = wgid % 6, mb = wgid / 6;
  int m0 = mb * 128, n0 = nb * 128;
  int l = t & 63, w = t >> 6, wr = w >> 1, wc = w & 1;
  int lr = l & 15, lg = l >> 4;
  int sw = (lr >> 1) & 3;
  f32x4_t acc[4][4];
  #pragma unroll
  for (int mi = 0; mi < 4; mi++)
    #pragma unroll
    for (int ni = 0; ni < 4; ni++) acc[mi][ni] = (f32x4_t){0.f, 0.f, 0.f, 0.f};

  auto stage = [&](int buf, int kt) {          // 2 A + 2 B gload16 per thread
    #pragma unroll
    for (int i = 0; i < 2; i++) {
      int off = t + i * 256;                   // 512 x 16B = 128x32 bf16
      int row = off >> 2, c = off & 3;
      int cs = c ^ ((row >> 1) & 3);           // inverse swizzle on SOURCE
      gload16(mg + (size_t)(m0 + row) * HID + kt * 32 + cs * 8, (char*)&Al[buf][0] + off * 16);
    }
    #pragma unroll
    for (int i = 0; i < 2; i++) {
      int off = t + i * 256;
      int row = off >> 2, c = off & 3;
      int cs = c ^ ((row >> 1) & 3);
      gload16(wb + (size_t)(n0 + row) * HID + kt * 32 + cs * 8, (char*)&Bl[buf][0] + off * 16);
    }
  };
  auto compute = [&](int cur) {                // 16 MFMAs (K=32 per step)
    __builtin_amdgcn_s_setprio(1);
    bf16x8_t a[4], bfr[4];
    int slot = lg ^ sw;
    #pragma unroll
    for (int mi = 0; mi < 4; mi++)
      a[mi] = *(const bf16x8_t*)(&Al[cur][(wr * 64 + mi * 16 + lr) * 32 + slot * 8]);
    #pragma unroll
    for (int ni = 0; ni < 4; ni++)
      bfr[ni] = *(const bf16x8_t*)(&Bl[cur][(wc * 64 + ni * 16 + lr) * 32 + slot * 8]);
    #pragma unroll
    for (int mi = 0; mi < 4; mi++)
      #pragma unroll
      for (int ni = 0; ni < 4; ni++)
        acc[mi][ni] = __builtin_amdgcn_mfma_f32_16x16x32_bf16(a[mi], bfr[ni], acc[mi][ni], 0, 0, 0);
    __builtin_amdgcn_s_setprio(0);
  };

  stage(0, 0);
  stage(1, 1);                                 // 8 loads in flight
  for (int kt = 0; kt < 23; kt++) {
    int cur = kt & 1;
    asm volatile("s_waitcnt vmcnt(4)" ::: "memory");     // stage(kt) landed; stage(kt+1) in flight
    __builtin_amdgcn_sched_barrier(0);
    __builtin_amdgcn_s_barrier();
    compute(cur);
    asm volatile("s_waitcnt lgkmcnt(0)" ::: "memory");   // my ds_reads of buf[cur] done
    __builtin_amdgcn_sched_barrier(0);
    __builtin_amdgcn_s_barrier();
    if (kt + 2 < 24) stage(cur, kt + 2);
  }
  asm volatile("s_waitcnt vmcnt(0)" ::: "memory");
  __builtin_amdgcn_sched_barrier(0);
  __builtin_amdgcn_s_barrier();
  compute(1);                                  // kt = 23

  #pragma unroll
  for (int ni = 0; ni < 4; ni++) {
    int col = n0 + wc * 64 + ni * 16 + lr;
    float bias = out_b[col];
    #pragma unroll
    for (int mi = 0; mi < 4; mi++) {
      #pragma unroll
      for (int r = 0; r < 4; r++) {
        int row = m0 + wr * 64 + mi * 16 + lg * 4 + r;
        out[(size_t)row * HID + col] = acc[mi][ni][r] + bias;
      }
    }
  }
}

extern "C" void kernel_launch(void* const* d_in, const int* in_sizes, int n_in,
                              void* d_out, int out_size, void* d_ws, size_t ws_size,
                              hipStream_t stream) {
  const float* hidden = (const float*)d_in[0];
  const float* lns    = (const float*)d_in[1];
  const float* lnb    = (const float*)d_in[2];
  const float* qkv_w  = (const float*)d_in[3];
  const float* qkv_b  = (const float*)d_in[4];
  const float* out_w  = (const float*)d_in[5];
  const float* out_b  = (const float*)d_in[6];
  char* ws = (char*)d_ws;
  unsigned short* qg  = (unsigned short*)(ws + 0);          // 16384*16*2      =   524288
  unsigned short* kg  = (unsigned short*)(ws + 524288);     // 16384*16*2      =   524288
  unsigned short* v16 = (unsigned short*)(ws + 1048576);    // 8*128*192*16*2  =  6291456
  unsigned short* qwb = (unsigned short*)(ws + 13631488);   // 208*192*2       =    79872
  unsigned short* wb  = (unsigned short*)(ws + 13711360);   // 768*768*2       =  1179648
  unsigned short* mg  = (unsigned short*)(ws + 14891008);   // 16384*768*2     = 25165824 (end 40056832)
  hipLaunchKernelGGL(k_prep_q, dim3(39),   dim3(256), 0, stream, qkv_w, qwb);
  hipLaunchKernelGGL(k_lnqkv,  dim3(1088), dim3(256), 0, stream, hidden, lns, lnb, qwb, qkv_b,
                     out_w, wb, mg, qg, kg, v16);
  hipLaunchKernelGGL(k_attn,   dim3(512),  dim3(256), 0, stream, qg, kg, v16, mg);
  hipLaunchKernelGGL(k_out,    dim3(768),  dim3(256), 0, stream, mg, wb, out_b, (float*)d_out);
}

// Round 18
// 92.580 us; speedup vs baseline: 1.1292x; 1.0132x over previous
//
#include <hip/hip_runtime.h>
#include <hip/hip_bf16.h>

#define HID 768
#define PD 164
#define NQ 196
#define SEQ 2048

typedef __attribute__((ext_vector_type(8))) short bf16x8_t;
typedef __attribute__((ext_vector_type(4))) float f32x4_t;
typedef __attribute__((ext_vector_type(16))) float f32x16_t;
typedef __attribute__((ext_vector_type(4))) unsigned int u32x4_t;

static __device__ __forceinline__ unsigned short f2bfu(float f) {
  union { __hip_bfloat16 h; unsigned short u; } cv;
  cv.h = __float2bfloat16(f);
  return cv.u;
}

static __device__ __forceinline__ unsigned cvtpk(float a, float b) {
  unsigned r;
  asm("v_cvt_pk_bf16_f32 %0, %1, %2" : "=v"(r) : "v"(a), "v"(b));
  return r;
}

static __device__ __forceinline__ void gload16(const void* g, void* l) {
  __builtin_amdgcn_global_load_lds(
      (const __attribute__((address_space(1))) void*)g,
      (__attribute__((address_space(3))) void*)l, 16, 0, 0);
}

// ---------------- prep: qkv_w -> bf16 (padded) only ----------------
__global__ __launch_bounds__(256) void k_prep_q(const float* __restrict__ qkv_w,
                                                unsigned short* __restrict__ qwb) {
  int i = (blockIdx.x * 256 + threadIdx.x) * 4;     // 208*192 = 39936 elems
  if (i >= 39936) return;
  int n = i / 192, k = i - n * 192;
  float v0 = (n < NQ && k + 0 < PD) ? qkv_w[n * PD + k + 0] : 0.f;
  float v1 = (n < NQ && k + 1 < PD) ? qkv_w[n * PD + k + 1] : 0.f;
  float v2 = (n < NQ && k + 2 < PD) ? qkv_w[n * PD + k + 2] : 0.f;
  float v3 = (n < NQ && k + 3 < PD) ? qkv_w[n * PD + k + 3] : 0.f;
  ushort4 o;
  o.x = f2bfu(v0); o.y = f2bfu(v1); o.z = f2bfu(v2); o.w = f2bfu(v3);
  *(ushort4*)(qwb + i) = o;
}

// ---------------- fused LN + x2 convert + QKV GEMM (+ wb convert blocks) ----------------
// v4: 16 rows/block x 1024 LN blocks = 4 blocks/CU (R17 was 2/CU; grid is the binder).
// LDS 17.1 KB. Stats: 16 lanes/row. GEMM: 4 waves share the 16-row A-tile, n-frags
// split {0-3},{4-6},{7-9},{10-12}. blocks 1024..1599: out_w -> wb convert.
__global__ __launch_bounds__(256, 4) void k_lnqkv(const float* __restrict__ hidden,
                                                  const float* __restrict__ lns,
                                                  const float* __restrict__ lnb,
                                                  const unsigned short* __restrict__ qwb,
                                                  const float* __restrict__ qkv_b,
                                                  const float* __restrict__ out_w,
                                                  unsigned short* __restrict__ wbo,
                                                  unsigned short* __restrict__ merged,
                                                  unsigned short* __restrict__ qg,
                                                  unsigned short* __restrict__ kg,
                                                  unsigned short* __restrict__ v16) {
  __shared__ float xr[16][172];
  __shared__ float stats[16][2];
  __shared__ unsigned short Aq[16][200];   // x1n bf16; cols 164..191 zero
  int t = threadIdx.x;
  if (blockIdx.x >= 1024) {                // ---- wb converter blocks ----
    int i = ((blockIdx.x - 1024) * 256 + t) * 4;    // 768*768 = 589824 elems
    float4 v = *(const float4*)(out_w + i);
    ushort4 o;
    o.x = f2bfu(v.x); o.y = f2bfu(v.y); o.z = f2bfu(v.z); o.w = f2bfu(v.w);
    *(ushort4*)(wbo + i) = o;
    return;
  }
  int r0 = blockIdx.x * 16;
  int l = t & 63, w = t >> 6;
  // ---- load x1 rows into LDS (16 rows x 41 quads = 656 float4) ----
  #pragma unroll
  for (int i = 0; i < 3; i++) {
    int idx = t + i * 256;
    if (idx < 656) {
      int row = idx / 41, q = idx - row * 41;
      float4 v = *(const float4*)(hidden + (size_t)(r0 + row) * HID + q * 4);
      *(float4*)&xr[row][q * 4] = v;
    }
  }
  __syncthreads();
  // ---- stats: 16 lanes per row (row = w*4 + (l>>4), g16 = l&15) ----
  {
    int row = w * 4 + (l >> 4), g16 = l & 15;
    float sum = 0.f, sq = 0.f;
    for (int j = g16; j < 41; j += 16) {
      float4 v = *(const float4*)&xr[row][j * 4];
      sum += v.x + v.y + v.z + v.w;
      sq  += v.x * v.x + v.y * v.y + v.z * v.z + v.w * v.w;
    }
    sum += __shfl_xor(sum, 1, 64); sum += __shfl_xor(sum, 2, 64);
    sum += __shfl_xor(sum, 4, 64); sum += __shfl_xor(sum, 8, 64);
    sq  += __shfl_xor(sq, 1, 64);  sq  += __shfl_xor(sq, 2, 64);
    sq  += __shfl_xor(sq, 4, 64);  sq  += __shfl_xor(sq, 8, 64);
    float mean = sum * (1.f / PD);
    float var = sq * (1.f / PD) - mean * mean;
    float rstd = rsqrtf(var + 1e-5f);
    if (g16 == 0) { stats[row][0] = mean; stats[row][1] = rstd; }
  }
  __syncthreads();
  // ---- normalize -> Aq bf16 (16 rows x 96 pairs = 1536) ----
  #pragma unroll
  for (int i = 0; i < 6; i++) {
    int idx = t + i * 256;
    int row = idx / 96, c2 = idx - row * 96;
    int d = c2 * 2;
    float mean = stats[row][0], rstd = stats[row][1];
    float v0 = (d < PD)     ? (xr[row][d]     - mean) * rstd * lns[d]     + lnb[d]     : 0.f;
    float v1 = (d + 1 < PD) ? (xr[row][d + 1] - mean) * rstd * lns[d + 1] + lnb[d + 1] : 0.f;
    unsigned int pk = (unsigned int)f2bfu(v0) | ((unsigned int)f2bfu(v1) << 16);
    *(unsigned int*)(&Aq[row][d]) = pk;
  }
  // ---- x2 convert -> merged (16 rows x 151 quads = 2416) ----
  #pragma unroll
  for (int i = 0; i < 10; i++) {
    int idx = t + i * 256;
    if (idx < 2416) {
      int row = idx / 151, q = idx - row * 151;
      int d = PD + q * 4;
      float4 v = *(const float4*)(hidden + (size_t)(r0 + row) * HID + d);
      ushort4 o;
      o.x = f2bfu(v.x); o.y = f2bfu(v.y); o.z = f2bfu(v.z); o.w = f2bfu(v.w);
      *(ushort4*)(merged + (size_t)(r0 + row) * HID + d) = o;
    }
  }
  __syncthreads();
  // ---- QKV GEMM: all waves share the 16-row A-tile; n-frags split across waves ----
  int lr15 = l & 15, g = l >> 4;
  const int nbase_t[4] = {0, 4, 7, 10};
  const int ncnt_t[4]  = {4, 3, 3, 3};
  int nbase = nbase_t[w], ncnt = ncnt_t[w];
  f32x4_t acc[4];
  #pragma unroll
  for (int n = 0; n < 4; n++) acc[n] = (f32x4_t){0.f, 0.f, 0.f, 0.f};
  #pragma unroll 2
  for (int kc = 0; kc < 6; kc++) {
    bf16x8_t a = *(const bf16x8_t*)(&Aq[lr15][kc * 32 + g * 8]);
    #pragma unroll
    for (int ni = 0; ni < 4; ni++) {
      if (ni < ncnt) {
        int n = nbase + ni;
        bf16x8_t b = *(const bf16x8_t*)(qwb + (size_t)(n * 16 + lr15) * 192 + kc * 32 + g * 8);
        acc[ni] = __builtin_amdgcn_mfma_f32_16x16x32_bf16(a, b, acc[ni], 0, 0, 0);
      }
    }
  }
  // ---- epilogue (per-wave n-ranges) ----
  int s0 = r0 & 2047;
  int bb = r0 >> 11;
  size_t vrowbase = (size_t)(bb * 128 + (s0 >> 4)) * 192;
  if (w == 0) {
    {
      float bias = qkv_b[lr15];
      #pragma unroll
      for (int r = 0; r < 4; r++) {
        int grow = r0 + g * 4 + r;
        qg[(size_t)grow * 16 + lr15] = f2bfu((acc[0][r] + bias) * 0.36067376022224085f); // 0.25*log2(e)
      }
    }
    {
      float bias = qkv_b[16 + lr15];
      #pragma unroll
      for (int r = 0; r < 4; r++) {
        int grow = r0 + g * 4 + r;
        kg[(size_t)grow * 16 + lr15] = f2bfu(acc[1][r] + bias);
      }
    }
    #pragma unroll
    for (int ni = 2; ni < 4; ni++) {
      int col = ni * 16 + lr15;
      int d = col - 32;                    // 0..31
      float bias = qkv_b[col];
      ushort4 o;
      o.x = f2bfu(acc[ni][0] + bias); o.y = f2bfu(acc[ni][1] + bias);
      o.z = f2bfu(acc[ni][2] + bias); o.w = f2bfu(acc[ni][3] + bias);
      *(ushort4*)(v16 + (vrowbase + d) * 16 + g * 4) = o;
    }
  } else {
    #pragma unroll
    for (int ni = 0; ni < 3; ni++) {
      if (ni < ncnt) {
        int col = (nbase + ni) * 16 + lr15;
        int d = col - 32;                  // 32..175
        float bias = (col < NQ) ? qkv_b[col] : 0.f;
        float v0 = acc[ni][0] + bias, v1 = acc[ni][1] + bias;
        float v2 = acc[ni][2] + bias, v3 = acc[ni][3] + bias;
        if (d == 164) { v0 = v1 = v2 = v3 = 1.f; }    // ones row: free denominator
        else if (d >= PD) { v0 = v1 = v2 = v3 = 0.f; }
        ushort4 o;
        o.x = f2bfu(v0); o.y = f2bfu(v1); o.z = f2bfu(v2); o.w = f2bfu(v3);
        *(ushort4*)(v16 + (vrowbase + d) * 16 + g * 4) = o;
      }
    }
  }
}

// ---------------- flash attention v5 (proven, FROZEN) ----------------
__global__ __launch_bounds__(256, 2) void k_attn(const unsigned short* __restrict__ qg,
                                                 const unsigned short* __restrict__ kg,
                                                 const unsigned short* __restrict__ v16,
                                                 unsigned short* __restrict__ merged) {
  __shared__ float red[2][64 * 98];
  int t = threadIdx.x;
  int w = t >> 6, l = t & 63;
  int b = blockIdx.x & 7, qt = blockIdx.x >> 3;
  int lo = l & 31, hi = l >> 5;
  int qbase = b * SEQ + qt * 32;
  bf16x8_t qf = *(const bf16x8_t*)(qg + (size_t)(qbase + lo) * 16 + hi * 8);
  const unsigned short* kb = kg + (size_t)b * SEQ * 16;
  const unsigned short* vbb = v16 + (size_t)b * 128 * 192 * 16;
  f32x16_t zro;
  #pragma unroll
  for (int r = 0; r < 16; r++) zro[r] = 0.f;
  f32x16_t acc[6];
  #pragma unroll
  for (int f = 0; f < 6; f++) acc[f] = zro;

  int it0 = w * 8;
  bf16x8_t kf0 = *(const bf16x8_t*)(kb + (size_t)(it0 * 64 + lo) * 16 + hi * 8);
  bf16x8_t kf1 = *(const bf16x8_t*)(kb + (size_t)(it0 * 64 + 32 + lo) * 16 + hi * 8);
  bf16x8_t va[6], vb_[6];
  {
    const unsigned short* vt0 = vbb + (size_t)(it0 * 4) * (192 * 16) + hi * 8;
    #pragma unroll
    for (int f = 0; f < 6; f++) va[f] = *(const bf16x8_t*)(vt0 + (f * 32 + lo) * 16);
  }
  for (int it = it0; it < it0 + 8; ++it) {
    bf16x8_t nk0 = *(const bf16x8_t*)(kb + (size_t)((it + 1) * 64 + lo) * 16 + hi * 8);
    bf16x8_t nk1 = *(const bf16x8_t*)(kb + (size_t)((it + 1) * 64 + 32 + lo) * 16 + hi * 8);
    f32x16_t sc0 = __builtin_amdgcn_mfma_f32_32x32x16_bf16(kf0, qf, zro, 0, 0, 0);
    f32x16_t sc1 = __builtin_amdgcn_mfma_f32_32x32x16_bf16(kf1, qf, zro, 0, 0, 0);
    bf16x8_t pa[4];
    #pragma unroll
    for (int jt = 0; jt < 2; ++jt) {
      f32x16_t sc = jt ? sc1 : sc0;
      unsigned u[8];
      #pragma unroll
      for (int k = 0; k < 8; ++k)
        u[k] = cvtpk(exp2f(sc[2 * k]), exp2f(sc[2 * k + 1]));
      asm volatile("v_permlane32_swap_b32 %0, %1" : "+v"(u[0]), "+v"(u[2]));
      asm volatile("v_permlane32_swap_b32 %0, %1" : "+v"(u[1]), "+v"(u[3]));
      asm volatile("v_permlane32_swap_b32 %0, %1" : "+v"(u[4]), "+v"(u[6]));
      asm volatile("v_permlane32_swap_b32 %0, %1" : "+v"(u[5]), "+v"(u[7]));
      union { u32x4_t u4; bf16x8_t h8; } c0, c1;
      c0.u4 = (u32x4_t){u[0], u[1], u[2], u[3]};
      c1.u4 = (u32x4_t){u[4], u[5], u[6], u[7]};
      pa[jt * 2 + 0] = c0.h8;
      pa[jt * 2 + 1] = c1.h8;
    }
#define PV_STEP(JS, VCUR, VNXT, NT, NJS)                                            \
    {                                                                               \
      const unsigned short* vtn = vbb + (size_t)((NT) * 4 + (NJS)) * (192 * 16) + hi * 8; \
      _Pragma("unroll")                                                             \
      for (int f = 0; f < 6; f++) VNXT[f] = *(const bf16x8_t*)(vtn + (f * 32 + lo) * 16); \
      _Pragma("unroll")                                                             \
      for (int f = 0; f < 6; f++)                                                   \
        acc[f] = __builtin_amdgcn_mfma_f32_32x32x16_bf16(pa[JS], VCUR[f], acc[f], 0, 0, 0); \
    }
    PV_STEP(0, va,  vb_, it, 1)
    PV_STEP(1, vb_, va,  it, 2)
    PV_STEP(2, va,  vb_, it, 3)
    PV_STEP(3, vb_, va,  it + 1, 0)
#undef PV_STEP
    kf0 = nk0; kf1 = nk1;
  }

  if (w >= 2) {
    float* dst = &red[w - 2][l * 98];
    #pragma unroll
    for (int f = 0; f < 6; f++)
      #pragma unroll
      for (int r = 0; r < 16; r += 2)
        *(float2*)(dst + f * 16 + r) = make_float2(acc[f][r], acc[f][r + 1]);
  }
  __syncthreads();
  if (w < 2) {
    const float* src = &red[w][l * 98];
    #pragma unroll
    for (int f = 0; f < 6; f++)
      #pragma unroll
      for (int r = 0; r < 16; r += 2) {
        float2 v = *(const float2*)(src + f * 16 + r);
        acc[f][r] += v.x; acc[f][r + 1] += v.y;
      }
  }
  __syncthreads();
  if (w == 1) {
    float* dst = &red[0][l * 98];
    #pragma unroll
    for (int f = 0; f < 6; f++)
      #pragma unroll
      for (int r = 0; r < 16; r += 2)
        *(float2*)(dst + f * 16 + r) = make_float2(acc[f][r], acc[f][r + 1]);
  }
  __syncthreads();
  if (w == 0) {
    const float* src = &red[0][l * 98];
    #pragma unroll
    for (int f = 0; f < 6; f++)
      #pragma unroll
      for (int r = 0; r < 16; r += 2) {
        float2 v = *(const float2*)(src + f * 16 + r);
        acc[f][r] += v.x; acc[f][r + 1] += v.y;
      }
    float dninv[16];
    #pragma unroll
    for (int r = 0; r < 16; ++r)
      dninv[r] = 1.0f / __shfl(acc[5][r], 4 + hi * 32, 64);
    #pragma unroll
    for (int f = 0; f < 6; ++f) {
      int d = f * 32 + lo;
      if (d < PD) {
        #pragma unroll
        for (int r = 0; r < 16; ++r) {
          int q = qbase + (r & 3) + 8 * (r >> 2) + 4 * hi;
          merged[(size_t)q * HID + d] = f2bfu(acc[f][r] * dninv[r]);
        }
      }
    }
  }
}

// ---------------- out GEMM v5 (R11 exact, proven ~33us — FROZEN) --------------------
__global__ __launch_bounds__(256, 3) void k_out(const unsigned short* __restrict__ mg,
                                                const unsigned short* __restrict__ wb,
                                                const float* __restrict__ out_b,
                                                float* __restrict__ out) {
  __shared__ unsigned short Al[2][128 * 32];   // 16 KB
  __shared__ unsigned short Bl[2][128 * 32];   // 16 KB
  int t = threadIdx.x;
  int bid = blockIdx.x;
  int wgid = (bid & 7) * 96 + (bid >> 3);      // bijective: 768 = 8*96
  int nb = wgid % 6, mb = wgid / 6;
  int m0 = mb * 128, n0 = nb * 128;
  int l = t & 63, w = t >> 6, wr = w >> 1, wc = w & 1;
  int lr = l & 15, lg = l >> 4;
  int sw = (lr >> 1) & 3;
  f32x4_t acc[4][4];
  #pragma unroll
  for (int mi = 0; mi < 4; mi++)
    #pragma unroll
    for (int ni = 0; ni < 4; ni++) acc[mi][ni] = (f32x4_t){0.f, 0.f, 0.f, 0.f};

  auto stage = [&](int buf, int kt) {          // 2 A + 2 B gload16 per thread
    #pragma unroll
    for (int i = 0; i < 2; i++) {
      int off = t + i * 256;                   // 512 x 16B = 128x32 bf16
      int row = off >> 2, c = off & 3;
      int cs = c ^ ((row >> 1) & 3);           // inverse swizzle on SOURCE
      gload16(mg + (size_t)(m0 + row) * HID + kt * 32 + cs * 8, (char*)&Al[buf][0] + off * 16);
    }
    #pragma unroll
    for (int i = 0; i < 2; i++) {
      int off = t + i * 256;
      int row = off >> 2, c = off & 3;
      int cs = c ^ ((row >> 1) & 3);
      gload16(wb + (size_t)(n0 + row) * HID + kt * 32 + cs * 8, (char*)&Bl[buf][0] + off * 16);
    }
  };
  auto compute = [&](int cur) {                // 16 MFMAs (K=32 per step)
    __builtin_amdgcn_s_setprio(1);
    bf16x8_t a[4], bfr[4];
    int slot = lg ^ sw;
    #pragma unroll
    for (int mi = 0; mi < 4; mi++)
      a[mi] = *(const bf16x8_t*)(&Al[cur][(wr * 64 + mi * 16 + lr) * 32 + slot * 8]);
    #pragma unroll
    for (int ni = 0; ni < 4; ni++)
      bfr[ni] = *(const bf16x8_t*)(&Bl[cur][(wc * 64 + ni * 16 + lr) * 32 + slot * 8]);
    #pragma unroll
    for (int mi = 0; mi < 4; mi++)
      #pragma unroll
      for (int ni = 0; ni < 4; ni++)
        acc[mi][ni] = __builtin_amdgcn_mfma_f32_16x16x32_bf16(a[mi], bfr[ni], acc[mi][ni], 0, 0, 0);
    __builtin_amdgcn_s_setprio(0);
  };

  stage(0, 0);
  stage(1, 1);                                 // 8 loads in flight
  for (int kt = 0; kt < 23; kt++) {
    int cur = kt & 1;
    asm volatile("s_waitcnt vmcnt(4)" ::: "memory");     // stage(kt) landed; stage(kt+1) in flight
    __builtin_amdgcn_sched_barrier(0);
    __builtin_amdgcn_s_barrier();
    compute(cur);
    asm volatile("s_waitcnt lgkmcnt(0)" ::: "memory");   // my ds_reads of buf[cur] done
    __builtin_amdgcn_sched_barrier(0);
    __builtin_amdgcn_s_barrier();
    if (kt + 2 < 24) stage(cur, kt + 2);
  }
  asm volatile("s_waitcnt vmcnt(0)" ::: "memory");
  __builtin_amdgcn_sched_barrier(0);
  __builtin_amdgcn_s_barrier();
  compute(1);                                  // kt = 23

  #pragma unroll
  for (int ni = 0; ni < 4; ni++) {
    int col = n0 + wc * 64 + ni * 16 + lr;
    float bias = out_b[col];
    #pragma unroll
    for (int mi = 0; mi < 4; mi++) {
      #pragma unroll
      for (int r = 0; r < 4; r++) {
        int row = m0 + wr * 64 + mi * 16 + lg * 4 + r;
        out[(size_t)row * HID + col] = acc[mi][ni][r] + bias;
      }
    }
  }
}

extern "C" void kernel_launch(void* const* d_in, const int* in_sizes, int n_in,
                              void* d_out, int out_size, void* d_ws, size_t ws_size,
                              hipStream_t stream) {
  const float* hidden = (const float*)d_in[0];
  const float* lns    = (const float*)d_in[1];
  const float* lnb    = (const float*)d_in[2];
  const float* qkv_w  = (const float*)d_in[3];
  const float* qkv_b  = (const float*)d_in[4];
  const float* out_w  = (const float*)d_in[5];
  const float* out_b  = (const float*)d_in[6];
  char* ws = (char*)d_ws;
  unsigned short* qg  = (unsigned short*)(ws + 0);          // 16384*16*2      =   524288
  unsigned short* kg  = (unsigned short*)(ws + 524288);     // 16384*16*2      =   524288
  unsigned short* v16 = (unsigned short*)(ws + 1048576);    // 8*128*192*16*2  =  6291456
  unsigned short* qwb = (unsigned short*)(ws + 13631488);   // 208*192*2       =    79872
  unsigned short* wb  = (unsigned short*)(ws + 13711360);   // 768*768*2       =  1179648
  unsigned short* mg  = (unsigned short*)(ws + 14891008);   // 16384*768*2     = 25165824 (end 40056832)
  hipLaunchKernelGGL(k_prep_q, dim3(39),   dim3(256), 0, stream, qkv_w, qwb);
  hipLaunchKernelGGL(k_lnqkv,  dim3(1600), dim3(256), 0, stream, hidden, lns, lnb, qwb, qkv_b,
                     out_w, wb, mg, qg, kg, v16);
  hipLaunchKernelGGL(k_attn,   dim3(512),  dim3(256), 0, stream, qg, kg, v16, mg);
  hipLaunchKernelGGL(k_out,    dim3(768),  dim3(256), 0, stream, mg, wb, out_b, (float*)d_out);
}

// Round 19
// 92.244 us; speedup vs baseline: 1.1334x; 1.0036x over previous
//
#include <hip/hip_runtime.h>
#include <hip/hip_bf16.h>

#define HID 768
#define PD 164
#define NQ 196
#define SEQ 2048

typedef __attribute__((ext_vector_type(8))) short bf16x8_t;
typedef __attribute__((ext_vector_type(4))) float f32x4_t;
typedef __attribute__((ext_vector_type(16))) float f32x16_t;
typedef __attribute__((ext_vector_type(4))) unsigned int u32x4_t;

static __device__ __forceinline__ unsigned short f2bfu(float f) {
  union { __hip_bfloat16 h; unsigned short u; } cv;
  cv.h = __float2bfloat16(f);
  return cv.u;
}

static __device__ __forceinline__ unsigned cvtpk(float a, float b) {
  unsigned r;
  asm("v_cvt_pk_bf16_f32 %0, %1, %2" : "=v"(r) : "v"(a), "v"(b));
  return r;
}

static __device__ __forceinline__ void gload16(const void* g, void* l) {
  __builtin_amdgcn_global_load_lds(
      (const __attribute__((address_space(1))) void*)g,
      (__attribute__((address_space(3))) void*)l, 16, 0, 0);
}

// ---------------- prep: qkv_w -> bf16 (padded) only ----------------
__global__ __launch_bounds__(256) void k_prep_q(const float* __restrict__ qkv_w,
                                                unsigned short* __restrict__ qwb) {
  int i = (blockIdx.x * 256 + threadIdx.x) * 4;     // 208*192 = 39936 elems
  if (i >= 39936) return;
  int n = i / 192, k = i - n * 192;
  float v0 = (n < NQ && k + 0 < PD) ? qkv_w[n * PD + k + 0] : 0.f;
  float v1 = (n < NQ && k + 1 < PD) ? qkv_w[n * PD + k + 1] : 0.f;
  float v2 = (n < NQ && k + 2 < PD) ? qkv_w[n * PD + k + 2] : 0.f;
  float v3 = (n < NQ && k + 3 < PD) ? qkv_w[n * PD + k + 3] : 0.f;
  ushort4 o;
  o.x = f2bfu(v0); o.y = f2bfu(v1); o.z = f2bfu(v2); o.w = f2bfu(v3);
  *(ushort4*)(qwb + i) = o;
}

// ---------------- fused LN + x2 convert + QKV GEMM (+ wb convert blocks) ----------------
// v5 = R18 v4 + T14 on the x2 phase: x2 float4 loads ISSUED before the barrier
// (drain under GEMM), convert+store AFTER the epilogue. xv[10] statically indexed.
__global__ __launch_bounds__(256, 4) void k_lnqkv(const float* __restrict__ hidden,
                                                  const float* __restrict__ lns,
                                                  const float* __restrict__ lnb,
                                                  const unsigned short* __restrict__ qwb,
                                                  const float* __restrict__ qkv_b,
                                                  const float* __restrict__ out_w,
                                                  unsigned short* __restrict__ wbo,
                                                  unsigned short* __restrict__ merged,
                                                  unsigned short* __restrict__ qg,
                                                  unsigned short* __restrict__ kg,
                                                  unsigned short* __restrict__ v16) {
  __shared__ float xr[16][172];
  __shared__ float stats[16][2];
  __shared__ unsigned short Aq[16][200];   // x1n bf16; cols 164..191 zero
  int t = threadIdx.x;
  if (blockIdx.x >= 1024) {                // ---- wb converter blocks ----
    int i = ((blockIdx.x - 1024) * 256 + t) * 4;    // 768*768 = 589824 elems
    float4 v = *(const float4*)(out_w + i);
    ushort4 o;
    o.x = f2bfu(v.x); o.y = f2bfu(v.y); o.z = f2bfu(v.z); o.w = f2bfu(v.w);
    *(ushort4*)(wbo + i) = o;
    return;
  }
  int r0 = blockIdx.x * 16;
  int l = t & 63, w = t >> 6;
  // ---- load x1 rows into LDS (16 rows x 41 quads = 656 float4) ----
  #pragma unroll
  for (int i = 0; i < 3; i++) {
    int idx = t + i * 256;
    if (idx < 656) {
      int row = idx / 41, q = idx - row * 41;
      float4 v = *(const float4*)(hidden + (size_t)(r0 + row) * HID + q * 4);
      *(float4*)&xr[row][q * 4] = v;
    }
  }
  __syncthreads();
  // ---- stats: 16 lanes per row (row = w*4 + (l>>4), g16 = l&15) ----
  {
    int row = w * 4 + (l >> 4), g16 = l & 15;
    float sum = 0.f, sq = 0.f;
    for (int j = g16; j < 41; j += 16) {
      float4 v = *(const float4*)&xr[row][j * 4];
      sum += v.x + v.y + v.z + v.w;
      sq  += v.x * v.x + v.y * v.y + v.z * v.z + v.w * v.w;
    }
    sum += __shfl_xor(sum, 1, 64); sum += __shfl_xor(sum, 2, 64);
    sum += __shfl_xor(sum, 4, 64); sum += __shfl_xor(sum, 8, 64);
    sq  += __shfl_xor(sq, 1, 64);  sq  += __shfl_xor(sq, 2, 64);
    sq  += __shfl_xor(sq, 4, 64);  sq  += __shfl_xor(sq, 8, 64);
    float mean = sum * (1.f / PD);
    float var = sq * (1.f / PD) - mean * mean;
    float rstd = rsqrtf(var + 1e-5f);
    if (g16 == 0) { stats[row][0] = mean; stats[row][1] = rstd; }
  }
  __syncthreads();
  // ---- normalize -> Aq bf16 (16 rows x 96 pairs = 1536) ----
  #pragma unroll
  for (int i = 0; i < 6; i++) {
    int idx = t + i * 256;
    int row = idx / 96, c2 = idx - row * 96;
    int d = c2 * 2;
    float mean = stats[row][0], rstd = stats[row][1];
    float v0 = (d < PD)     ? (xr[row][d]     - mean) * rstd * lns[d]     + lnb[d]     : 0.f;
    float v1 = (d + 1 < PD) ? (xr[row][d + 1] - mean) * rstd * lns[d + 1] + lnb[d + 1] : 0.f;
    unsigned int pk = (unsigned int)f2bfu(v0) | ((unsigned int)f2bfu(v1) << 16);
    *(unsigned int*)(&Aq[row][d]) = pk;
  }
  // ---- T14 issue-early: x2 float4 loads into regs (drain under GEMM) ----
  float4 xv[10];
  #pragma unroll
  for (int i = 0; i < 10; i++) {
    int idx = t + i * 256;                 // 16 rows x 151 quads = 2416
    if (idx < 2416) {
      int row = idx / 151, q = idx - row * 151;
      xv[i] = *(const float4*)(hidden + (size_t)(r0 + row) * HID + PD + q * 4);
    }
  }
  __syncthreads();
  // ---- QKV GEMM: all waves share the 16-row A-tile; n-frags split across waves ----
  int lr15 = l & 15, g = l >> 4;
  const int nbase_t[4] = {0, 4, 7, 10};
  const int ncnt_t[4]  = {4, 3, 3, 3};
  int nbase = nbase_t[w], ncnt = ncnt_t[w];
  f32x4_t acc[4];
  #pragma unroll
  for (int n = 0; n < 4; n++) acc[n] = (f32x4_t){0.f, 0.f, 0.f, 0.f};
  #pragma unroll 2
  for (int kc = 0; kc < 6; kc++) {
    bf16x8_t a = *(const bf16x8_t*)(&Aq[lr15][kc * 32 + g * 8]);
    #pragma unroll
    for (int ni = 0; ni < 4; ni++) {
      if (ni < ncnt) {
        int n = nbase + ni;
        bf16x8_t b = *(const bf16x8_t*)(qwb + (size_t)(n * 16 + lr15) * 192 + kc * 32 + g * 8);
        acc[ni] = __builtin_amdgcn_mfma_f32_16x16x32_bf16(a, b, acc[ni], 0, 0, 0);
      }
    }
  }
  // ---- epilogue (per-wave n-ranges) ----
  int s0 = r0 & 2047;
  int bb = r0 >> 11;
  size_t vrowbase = (size_t)(bb * 128 + (s0 >> 4)) * 192;
  if (w == 0) {
    {
      float bias = qkv_b[lr15];
      #pragma unroll
      for (int r = 0; r < 4; r++) {
        int grow = r0 + g * 4 + r;
        qg[(size_t)grow * 16 + lr15] = f2bfu((acc[0][r] + bias) * 0.36067376022224085f); // 0.25*log2(e)
      }
    }
    {
      float bias = qkv_b[16 + lr15];
      #pragma unroll
      for (int r = 0; r < 4; r++) {
        int grow = r0 + g * 4 + r;
        kg[(size_t)grow * 16 + lr15] = f2bfu(acc[1][r] + bias);
      }
    }
    #pragma unroll
    for (int ni = 2; ni < 4; ni++) {
      int col = ni * 16 + lr15;
      int d = col - 32;                    // 0..31
      float bias = qkv_b[col];
      ushort4 o;
      o.x = f2bfu(acc[ni][0] + bias); o.y = f2bfu(acc[ni][1] + bias);
      o.z = f2bfu(acc[ni][2] + bias); o.w = f2bfu(acc[ni][3] + bias);
      *(ushort4*)(v16 + (vrowbase + d) * 16 + g * 4) = o;
    }
  } else {
    #pragma unroll
    for (int ni = 0; ni < 3; ni++) {
      if (ni < ncnt) {
        int col = (nbase + ni) * 16 + lr15;
        int d = col - 32;                  // 32..175
        float bias = (col < NQ) ? qkv_b[col] : 0.f;
        float v0 = acc[ni][0] + bias, v1 = acc[ni][1] + bias;
        float v2 = acc[ni][2] + bias, v3 = acc[ni][3] + bias;
        if (d == 164) { v0 = v1 = v2 = v3 = 1.f; }    // ones row: free denominator
        else if (d >= PD) { v0 = v1 = v2 = v3 = 0.f; }
        ushort4 o;
        o.x = f2bfu(v0); o.y = f2bfu(v1); o.z = f2bfu(v2); o.w = f2bfu(v3);
        *(ushort4*)(v16 + (vrowbase + d) * 16 + g * 4) = o;
      }
    }
  }
  // ---- T14 consume-late: x2 convert + store ----
  #pragma unroll
  for (int i = 0; i < 10; i++) {
    int idx = t + i * 256;
    if (idx < 2416) {
      int row = idx / 151, q = idx - row * 151;
      int d = PD + q * 4;
      ushort4 o;
      o.x = f2bfu(xv[i].x); o.y = f2bfu(xv[i].y);
      o.z = f2bfu(xv[i].z); o.w = f2bfu(xv[i].w);
      *(ushort4*)(merged + (size_t)(r0 + row) * HID + d) = o;
    }
  }
}

// ---------------- flash attention v5 (proven, FROZEN) ----------------
__global__ __launch_bounds__(256, 2) void k_attn(const unsigned short* __restrict__ qg,
                                                 const unsigned short* __restrict__ kg,
                                                 const unsigned short* __restrict__ v16,
                                                 unsigned short* __restrict__ merged) {
  __shared__ float red[2][64 * 98];
  int t = threadIdx.x;
  int w = t >> 6, l = t & 63;
  int b = blockIdx.x & 7, qt = blockIdx.x >> 3;
  int lo = l & 31, hi = l >> 5;
  int qbase = b * SEQ + qt * 32;
  bf16x8_t qf = *(const bf16x8_t*)(qg + (size_t)(qbase + lo) * 16 + hi * 8);
  const unsigned short* kb = kg + (size_t)b * SEQ * 16;
  const unsigned short* vbb = v16 + (size_t)b * 128 * 192 * 16;
  f32x16_t zro;
  #pragma unroll
  for (int r = 0; r < 16; r++) zro[r] = 0.f;
  f32x16_t acc[6];
  #pragma unroll
  for (int f = 0; f < 6; f++) acc[f] = zro;

  int it0 = w * 8;
  bf16x8_t kf0 = *(const bf16x8_t*)(kb + (size_t)(it0 * 64 + lo) * 16 + hi * 8);
  bf16x8_t kf1 = *(const bf16x8_t*)(kb + (size_t)(it0 * 64 + 32 + lo) * 16 + hi * 8);
  bf16x8_t va[6], vb_[6];
  {
    const unsigned short* vt0 = vbb + (size_t)(it0 * 4) * (192 * 16) + hi * 8;
    #pragma unroll
    for (int f = 0; f < 6; f++) va[f] = *(const bf16x8_t*)(vt0 + (f * 32 + lo) * 16);
  }
  for (int it = it0; it < it0 + 8; ++it) {
    bf16x8_t nk0 = *(const bf16x8_t*)(kb + (size_t)((it + 1) * 64 + lo) * 16 + hi * 8);
    bf16x8_t nk1 = *(const bf16x8_t*)(kb + (size_t)((it + 1) * 64 + 32 + lo) * 16 + hi * 8);
    f32x16_t sc0 = __builtin_amdgcn_mfma_f32_32x32x16_bf16(kf0, qf, zro, 0, 0, 0);
    f32x16_t sc1 = __builtin_amdgcn_mfma_f32_32x32x16_bf16(kf1, qf, zro, 0, 0, 0);
    bf16x8_t pa[4];
    #pragma unroll
    for (int jt = 0; jt < 2; ++jt) {
      f32x16_t sc = jt ? sc1 : sc0;
      unsigned u[8];
      #pragma unroll
      for (int k = 0; k < 8; ++k)
        u[k] = cvtpk(exp2f(sc[2 * k]), exp2f(sc[2 * k + 1]));
      asm volatile("v_permlane32_swap_b32 %0, %1" : "+v"(u[0]), "+v"(u[2]));
      asm volatile("v_permlane32_swap_b32 %0, %1" : "+v"(u[1]), "+v"(u[3]));
      asm volatile("v_permlane32_swap_b32 %0, %1" : "+v"(u[4]), "+v"(u[6]));
      asm volatile("v_permlane32_swap_b32 %0, %1" : "+v"(u[5]), "+v"(u[7]));
      union { u32x4_t u4; bf16x8_t h8; } c0, c1;
      c0.u4 = (u32x4_t){u[0], u[1], u[2], u[3]};
      c1.u4 = (u32x4_t){u[4], u[5], u[6], u[7]};
      pa[jt * 2 + 0] = c0.h8;
      pa[jt * 2 + 1] = c1.h8;
    }
#define PV_STEP(JS, VCUR, VNXT, NT, NJS)                                            \
    {                                                                               \
      const unsigned short* vtn = vbb + (size_t)((NT) * 4 + (NJS)) * (192 * 16) + hi * 8; \
      _Pragma("unroll")                                                             \
      for (int f = 0; f < 6; f++) VNXT[f] = *(const bf16x8_t*)(vtn + (f * 32 + lo) * 16); \
      _Pragma("unroll")                                                             \
      for (int f = 0; f < 6; f++)                                                   \
        acc[f] = __builtin_amdgcn_mfma_f32_32x32x16_bf16(pa[JS], VCUR[f], acc[f], 0, 0, 0); \
    }
    PV_STEP(0, va,  vb_, it, 1)
    PV_STEP(1, vb_, va,  it, 2)
    PV_STEP(2, va,  vb_, it, 3)
    PV_STEP(3, vb_, va,  it + 1, 0)
#undef PV_STEP
    kf0 = nk0; kf1 = nk1;
  }

  if (w >= 2) {
    float* dst = &red[w - 2][l * 98];
    #pragma unroll
    for (int f = 0; f < 6; f++)
      #pragma unroll
      for (int r = 0; r < 16; r += 2)
        *(float2*)(dst + f * 16 + r) = make_float2(acc[f][r], acc[f][r + 1]);
  }
  __syncthreads();
  if (w < 2) {
    const float* src = &red[w][l * 98];
    #pragma unroll
    for (int f = 0; f < 6; f++)
      #pragma unroll
      for (int r = 0; r < 16; r += 2) {
        float2 v = *(const float2*)(src + f * 16 + r);
        acc[f][r] += v.x; acc[f][r + 1] += v.y;
      }
  }
  __syncthreads();
  if (w == 1) {
    float* dst = &red[0][l * 98];
    #pragma unroll
    for (int f = 0; f < 6; f++)
      #pragma unroll
      for (int r = 0; r < 16; r += 2)
        *(float2*)(dst + f * 16 + r) = make_float2(acc[f][r], acc[f][r + 1]);
  }
  __syncthreads();
  if (w == 0) {
    const float* src = &red[0][l * 98];
    #pragma unroll
    for (int f = 0; f < 6; f++)
      #pragma unroll
      for (int r = 0; r < 16; r += 2) {
        float2 v = *(const float2*)(src + f * 16 + r);
        acc[f][r] += v.x; acc[f][r + 1] += v.y;
      }
    float dninv[16];
    #pragma unroll
    for (int r = 0; r < 16; ++r)
      dninv[r] = 1.0f / __shfl(acc[5][r], 4 + hi * 32, 64);
    #pragma unroll
    for (int f = 0; f < 6; ++f) {
      int d = f * 32 + lo;
      if (d < PD) {
        #pragma unroll
        for (int r = 0; r < 16; ++r) {
          int q = qbase + (r & 3) + 8 * (r >> 2) + 4 * hi;
          merged[(size_t)q * HID + d] = f2bfu(acc[f][r] * dninv[r]);
        }
      }
    }
  }
}

// ---------------- out GEMM v5 (R11 exact, proven ~33us — FROZEN) --------------------
__global__ __launch_bounds__(256, 3) void k_out(const unsigned short* __restrict__ mg,
                                                const unsigned short* __restrict__ wb,
                                                const float* __restrict__ out_b,
                                                float* __restrict__ out) {
  __shared__ unsigned short Al[2][128 * 32];   // 16 KB
  __shared__ unsigned short Bl[2][128 * 32];   // 16 KB
  int t = threadIdx.x;
  int bid = blockIdx.x;
  int wgid = (bid & 7) * 96 + (bid >> 3);      // bijective: 768 = 8*96
  int nb = wgid % 6, mb = wgid / 6;
  int m0 = mb * 128, n0 = nb * 128;
  int l = t & 63, w = t >> 6, wr = w >> 1, wc = w & 1;
  int lr = l & 15, lg = l >> 4;
  int sw = (lr >> 1) & 3;
  f32x4_t acc[4][4];
  #pragma unroll
  for (int mi = 0; mi < 4; mi++)
    #pragma unroll
    for (int ni = 0; ni < 4; ni++) acc[mi][ni] = (f32x4_t){0.f, 0.f, 0.f, 0.f};

  auto stage = [&](int buf, int kt) {          // 2 A + 2 B gload16 per thread
    #pragma unroll
    for (int i = 0; i < 2; i++) {
      int off = t + i * 256;                   // 512 x 16B = 128x32 bf16
      int row = off >> 2, c = off & 3;
      int cs = c ^ ((row >> 1) & 3);           // inverse swizzle on SOURCE
      gload16(mg + (size_t)(m0 + row) * HID + kt * 32 + cs * 8, (char*)&Al[buf][0] + off * 16);
    }
    #pragma unroll
    for (int i = 0; i < 2; i++) {
      int off = t + i * 256;
      int row = off >> 2, c = off & 3;
      int cs = c ^ ((row >> 1) & 3);
      gload16(wb + (size_t)(n0 + row) * HID + kt * 32 + cs * 8, (char*)&Bl[buf][0] + off * 16);
    }
  };
  auto compute = [&](int cur) {                // 16 MFMAs (K=32 per step)
    __builtin_amdgcn_s_setprio(1);
    bf16x8_t a[4], bfr[4];
    int slot = lg ^ sw;
    #pragma unroll
    for (int mi = 0; mi < 4; mi++)
      a[mi] = *(const bf16x8_t*)(&Al[cur][(wr * 64 + mi * 16 + lr) * 32 + slot * 8]);
    #pragma unroll
    for (int ni = 0; ni < 4; ni++)
      bfr[ni] = *(const bf16x8_t*)(&Bl[cur][(wc * 64 + ni * 16 + lr) * 32 + slot * 8]);
    #pragma unroll
    for (int mi = 0; mi < 4; mi++)
      #pragma unroll
      for (int ni = 0; ni < 4; ni++)
        acc[mi][ni] = __builtin_amdgcn_mfma_f32_16x16x32_bf16(a[mi], bfr[ni], acc[mi][ni], 0, 0, 0);
    __builtin_amdgcn_s_setprio(0);
  };

  stage(0, 0);
  stage(1, 1);                                 // 8 loads in flight
  for (int kt = 0; kt < 23; kt++) {
    int cur = kt & 1;
    asm volatile("s_waitcnt vmcnt(4)" ::: "memory");     // stage(kt) landed; stage(kt+1) in flight
    __builtin_amdgcn_sched_barrier(0);
    __builtin_amdgcn_s_barrier();
    compute(cur);
    asm volatile("s_waitcnt lgkmcnt(0)" ::: "memory");   // my ds_reads of buf[cur] done
    __builtin_amdgcn_sched_barrier(0);
    __builtin_amdgcn_s_barrier();
    if (kt + 2 < 24) stage(cur, kt + 2);
  }
  asm volatile("s_waitcnt vmcnt(0)" ::: "memory");
  __builtin_amdgcn_sched_barrier(0);
  __builtin_amdgcn_s_barrier();
  compute(1);                                  // kt = 23

  #pragma unroll
  for (int ni = 0; ni < 4; ni++) {
    int col = n0 + wc * 64 + ni * 16 + lr;
    float bias = out_b[col];
    #pragma unroll
    for (int mi = 0; mi < 4; mi++) {
      #pragma unroll
      for (int r = 0; r < 4; r++) {
        int row = m0 + wr * 64 + mi * 16 + lg * 4 + r;
        out[(size_t)row * HID + col] = acc[mi][ni][r] + bias;
      }
    }
  }
}

extern "C" void kernel_launch(void* const* d_in, const int* in_sizes, int n_in,
                              void* d_out, int out_size, void* d_ws, size_t ws_size,
                              hipStream_t stream) {
  const float* hidden = (const float*)d_in[0];
  const float* lns    = (const float*)d_in[1];
  const float* lnb    = (const float*)d_in[2];
  const float* qkv_w  = (const float*)d_in[3];
  const float* qkv_b  = (const float*)d_in[4];
  const float* out_w  = (const float*)d_in[5];
  const float* out_b  = (const float*)d_in[6];
  char* ws = (char*)d_ws;
  unsigned short* qg  = (unsigned short*)(ws + 0);          // 16384*16*2      =   524288
  unsigned short* kg  = (unsigned short*)(ws + 524288);     // 16384*16*2      =   524288
  unsigned short* v16 = (unsigned short*)(ws + 1048576);    // 8*128*192*16*2  =  6291456
  unsigned short* qwb = (unsigned short*)(ws + 13631488);   // 208*192*2       =    79872
  unsigned short* wb  = (unsigned short*)(ws + 13711360);   // 768*768*2       =  1179648
  unsigned short* mg  = (unsigned short*)(ws + 14891008);   // 16384*768*2     = 25165824 (end 40056832)
  hipLaunchKernelGGL(k_prep_q, dim3(39),   dim3(256), 0, stream, qkv_w, qwb);
  hipLaunchKernelGGL(k_lnqkv,  dim3(1600), dim3(256), 0, stream, hidden, lns, lnb, qwb, qkv_b,
                     out_w, wb, mg, qg, kg, v16);
  hipLaunchKernelGGL(k_attn,   dim3(512),  dim3(256), 0, stream, qg, kg, v16, mg);
  hipLaunchKernelGGL(k_out,    dim3(768),  dim3(256), 0, stream, mg, wb, out_b, (float*)d_out);
}